// Round 1
// baseline (224.392 us; speedup 1.0000x reference)
//
#include <hip/hip_runtime.h>

#define N_NODES 100000
#define DEG 16
#define D_DIM 128
#define U_DIM 128
#define M_TILE 128
#define AGG_STRIDE 136   // 128 + 8 bf16 pad -> 272 B row stride, breaks LDS bank aliasing

typedef __bf16 bf16x8 __attribute__((ext_vector_type(8)));
typedef float f32x4 __attribute__((ext_vector_type(4)));

__device__ __forceinline__ unsigned short f2bf(float x) {
    // round-to-nearest-even fp32 -> bf16 (inputs are finite)
    unsigned int u = __float_as_uint(x);
    u += 0x7fffu + ((u >> 16) & 1u);
    return (unsigned short)(u >> 16);
}

// feat fp32 [N,128] -> bf16, 4 elems/thread, exact grid (12.8M / 4 / 256 = 12500)
__global__ void cast_feat_kernel(const float* __restrict__ f,
                                 unsigned short* __restrict__ o) {
    int i = blockIdx.x * 256 + threadIdx.x;
    float4 v = ((const float4*)f)[i];
    ushort4 r;
    r.x = f2bf(v.x); r.y = f2bf(v.y); r.z = f2bf(v.z); r.w = f2bf(v.w);
    ((ushort4*)o)[i] = r;
}

// W fp32 [K=128][U=128] row-major -> WT bf16 [U][K] (B-fragment friendly: k contiguous)
__global__ void cast_w_kernel(const float* __restrict__ W,
                              unsigned short* __restrict__ WT) {
    int t = blockIdx.x * 256 + threadIdx.x;   // t < 16384
    int k = t >> 7, n = t & 127;
    WT[n * 128 + k] = f2bf(W[t]);
}

// Fused: gather-aggregate 128 nodes into LDS (bf16), then [128x128]@[128x128] bf16 MFMA
template <bool BF16FEAT>
__global__ __launch_bounds__(256)
void gconv_kernel(const float* __restrict__ feat_f32,
                  const unsigned int* __restrict__ feat_bf2,   // bf16 pairs, [N][64] dwords
                  const int* __restrict__ cols,
                  const float* __restrict__ wts,
                  const unsigned short* __restrict__ WT,       // bf16 [U][K]
                  const float* __restrict__ bias,
                  float* __restrict__ out) {
    __shared__ __align__(16) unsigned short agg[M_TILE * AGG_STRIDE];
    const int lane = threadIdx.x & 63;
    const int wv = threadIdx.x >> 6;
    const int block0 = blockIdx.x * M_TILE;

    // ---- phase 1: each wave aggregates 32 nodes; lane handles dims 2*lane, 2*lane+1 ----
    for (int it = 0; it < 32; ++it) {
        const int n_local = wv * 32 + it;
        const int node = block0 + n_local;
        float ax = 0.f, ay = 0.f, den = 0.f;
        if (node < N_NODES) {
            const int e0 = node * DEG;
            const int4* cp = (const int4*)(cols + e0);     // 64 B aligned
            const float4* wp = (const float4*)(wts + e0);
            #pragma unroll
            for (int q = 0; q < 4; ++q) {
                const int4 c4 = cp[q];
                const float4 w4 = wp[q];
                const int cc[4] = {c4.x, c4.y, c4.z, c4.w};
                const float ww[4] = {w4.x, w4.y, w4.z, w4.w};
                #pragma unroll
                for (int e = 0; e < 4; ++e) {
                    float fx, fy;
                    if (BF16FEAT) {
                        const unsigned int p = feat_bf2[cc[e] * 64 + lane];
                        fx = __uint_as_float(p << 16);
                        fy = __uint_as_float(p & 0xffff0000u);
                    } else {
                        const float2 f2 = *(const float2*)(feat_f32 + (size_t)cc[e] * D_DIM + lane * 2);
                        fx = f2.x; fy = f2.y;
                    }
                    ax = fmaf(ww[e], fx, ax);
                    ay = fmaf(ww[e], fy, ay);
                    den += ww[e];
                }
            }
        }
        const float inv = (node < N_NODES) ? (1.0f / den) : 0.f;   // den >= 1.6 when valid
        const unsigned int packed =
            (unsigned int)f2bf(ax * inv) | ((unsigned int)f2bf(ay * inv) << 16);
        *(unsigned int*)&agg[n_local * AGG_STRIDE + lane * 2] = packed;
    }
    __syncthreads();

    // ---- phase 2: wave w computes rows [32w, 32w+32) x all 128 cols via 16x16x32 MFMA ----
    const int quad = lane >> 4;
    const int l15 = lane & 15;
    f32x4 acc[2][8];
    #pragma unroll
    for (int mi = 0; mi < 2; ++mi)
        #pragma unroll
        for (int ni = 0; ni < 8; ++ni)
            acc[mi][ni] = (f32x4){0.f, 0.f, 0.f, 0.f};

    #pragma unroll
    for (int kc = 0; kc < 4; ++kc) {
        bf16x8 bfr[8];
        #pragma unroll
        for (int ni = 0; ni < 8; ++ni)   // B[k][n]: n = l15 + 16*ni, k = kc*32 + quad*8 + j
            bfr[ni] = *(const bf16x8*)(WT + (ni * 16 + l15) * 128 + kc * 32 + quad * 8);
        bf16x8 afr[2];
        #pragma unroll
        for (int mi = 0; mi < 2; ++mi)   // A[m][k]: m = wave rows + l15
            afr[mi] = *(const bf16x8*)&agg[(wv * 32 + mi * 16 + l15) * AGG_STRIDE + kc * 32 + quad * 8];
        #pragma unroll
        for (int mi = 0; mi < 2; ++mi)
            #pragma unroll
            for (int ni = 0; ni < 8; ++ni)
                acc[mi][ni] = __builtin_amdgcn_mfma_f32_16x16x32_bf16(afr[mi], bfr[ni], acc[mi][ni], 0, 0, 0);
    }

    // ---- epilogue: D[row][col], row = quad*4 + r, col = l15; bias + relu + store ----
    #pragma unroll
    for (int ni = 0; ni < 8; ++ni) {
        const int col = ni * 16 + l15;
        const float bv = bias[col];
        #pragma unroll
        for (int mi = 0; mi < 2; ++mi) {
            #pragma unroll
            for (int r = 0; r < 4; ++r) {
                const int row = wv * 32 + mi * 16 + quad * 4 + r;
                const int node = block0 + row;
                if (node < N_NODES)
                    out[(size_t)node * U_DIM + col] = fmaxf(acc[mi][ni][r] + bv, 0.f);
            }
        }
    }
}

extern "C" void kernel_launch(void* const* d_in, const int* in_sizes, int n_in,
                              void* d_out, int out_size, void* d_ws, size_t ws_size,
                              hipStream_t stream) {
    const float* feat = (const float*)d_in[0];
    // d_in[1] = edge_rows: unused — rows are arange(E)//16, i.e. node i owns edges [16i,16i+16)
    const int* cols  = (const int*)d_in[2];
    const float* wts = (const float*)d_in[3];
    const float* W   = (const float*)d_in[4];
    const float* b   = (const float*)d_in[5];
    float* out = (float*)d_out;

    unsigned short* wt_bf   = (unsigned short*)d_ws;                    // 32 KB
    unsigned short* feat_bf = (unsigned short*)((char*)d_ws + 32768);   // 25.6 MB
    const size_t need = 32768 + (size_t)N_NODES * D_DIM * 2;
    const bool bf16path = ws_size >= need;

    cast_w_kernel<<<16384 / 256, 256, 0, stream>>>(W, wt_bf);

    const int nblocks = (N_NODES + M_TILE - 1) / M_TILE;   // 782
    if (bf16path) {
        cast_feat_kernel<<<(N_NODES * D_DIM / 4) / 256, 256, 0, stream>>>(feat, feat_bf);
        gconv_kernel<true><<<nblocks, 256, 0, stream>>>(
            nullptr, (const unsigned int*)feat_bf, cols, wts, wt_bf, b, out);
    } else {
        gconv_kernel<false><<<nblocks, 256, 0, stream>>>(
            feat, nullptr, cols, wts, wt_bf, b, out);
    }
}

// Round 2
// 185.175 us; speedup vs baseline: 1.2118x; 1.2118x over previous
//
#include <hip/hip_runtime.h>

#define N_NODES 100000
#define DEG 16
#define D_DIM 128
#define U_DIM 128
#define M_TILE 128

typedef __bf16 bf16x8 __attribute__((ext_vector_type(8)));
typedef float f32x4 __attribute__((ext_vector_type(4)));

__device__ __forceinline__ unsigned short f2bf(float x) {
    // round-to-nearest-even fp32 -> bf16 (inputs finite)
    unsigned int u = __float_as_uint(x);
    u += 0x7fffu + ((u >> 16) & 1u);
    return (unsigned short)(u >> 16);
}

// W fp32 [K=128][U=128] row-major -> WT bf16 [U][K] (B-fragment friendly: k contiguous)
__global__ void cast_w_kernel(const float* __restrict__ W,
                              unsigned short* __restrict__ WT) {
    int t = blockIdx.x * 256 + threadIdx.x;   // t < 16384
    int k = t >> 7, n = t & 127;
    WT[n * 128 + k] = f2bf(W[t]);
}

// Y = feat @ W  (bf16 MFMA, fp32 acc), Y stored bf16 [N][128].
// 128-row tile per block, wave w owns rows [32w,32w+32).
__global__ __launch_bounds__(256)
void ymat_kernel(const float* __restrict__ feat,
                 const unsigned short* __restrict__ WT,   // bf16 [U][K]
                 unsigned short* __restrict__ Y) {
    const int lane = threadIdx.x & 63;
    const int wv = threadIdx.x >> 6;
    const int block0 = blockIdx.x * M_TILE;
    const int quad = lane >> 4;
    const int l15 = lane & 15;

    f32x4 acc[2][8];
    #pragma unroll
    for (int mi = 0; mi < 2; ++mi)
        #pragma unroll
        for (int ni = 0; ni < 8; ++ni)
            acc[mi][ni] = (f32x4){0.f, 0.f, 0.f, 0.f};

    #pragma unroll
    for (int kc = 0; kc < 4; ++kc) {
        bf16x8 bfr[8];
        #pragma unroll
        for (int ni = 0; ni < 8; ++ni)   // B[k][n]: n = l15+16ni, k = kc*32+quad*8+j
            bfr[ni] = *(const bf16x8*)(WT + (ni * 16 + l15) * 128 + kc * 32 + quad * 8);
        bf16x8 afr[2];
        #pragma unroll
        for (int mi = 0; mi < 2; ++mi) {
            int row = block0 + wv * 32 + mi * 16 + l15;
            if (row >= N_NODES) row = N_NODES - 1;       // clamp; store is guarded
            const float* ap = feat + (size_t)row * D_DIM + kc * 32 + quad * 8;
            const float4 a0 = *(const float4*)ap;
            const float4 a1 = *(const float4*)(ap + 4);
            union { unsigned short us[8]; bf16x8 b; } pk;
            pk.us[0] = f2bf(a0.x); pk.us[1] = f2bf(a0.y);
            pk.us[2] = f2bf(a0.z); pk.us[3] = f2bf(a0.w);
            pk.us[4] = f2bf(a1.x); pk.us[5] = f2bf(a1.y);
            pk.us[6] = f2bf(a1.z); pk.us[7] = f2bf(a1.w);
            afr[mi] = pk.b;
        }
        #pragma unroll
        for (int mi = 0; mi < 2; ++mi)
            #pragma unroll
            for (int ni = 0; ni < 8; ++ni)
                acc[mi][ni] = __builtin_amdgcn_mfma_f32_16x16x32_bf16(afr[mi], bfr[ni], acc[mi][ni], 0, 0, 0);
    }

    // D[row][col]: row = quad*4+r, col = l15 (+16ni)
    #pragma unroll
    for (int mi = 0; mi < 2; ++mi)
        #pragma unroll
        for (int r = 0; r < 4; ++r) {
            const int row = block0 + wv * 32 + mi * 16 + quad * 4 + r;
            if (row < N_NODES) {
                #pragma unroll
                for (int ni = 0; ni < 8; ++ni)
                    Y[(size_t)row * U_DIM + ni * 16 + l15] = f2bf(acc[mi][ni][r]);
            }
        }
}

// out[i] = relu( (sum_e w_e * Y[col_e]) / (sum_e w_e) + b )
// One wave per node; lane holds dims {2*lane, 2*lane+1}. Pure gather, no LDS.
__global__ __launch_bounds__(256, 6)
void agg_kernel(const unsigned int* __restrict__ Ybf2,   // bf16 pairs [N][64] dwords
                const int* __restrict__ cols,
                const float* __restrict__ wts,
                const float* __restrict__ bias,
                float* __restrict__ out) {
    const int node = blockIdx.x * 4 + (threadIdx.x >> 6);   // grid exact: 25000*4 = N
    const int lane = threadIdx.x & 63;
    const int e0 = node * DEG;

    // wave-uniform edge data -> scalar loads
    int cc[DEG];
    float ww[DEG];
    #pragma unroll
    for (int q = 0; q < 4; ++q) {
        const int4 c4 = *(const int4*)(cols + e0 + q * 4);
        const float4 w4 = *(const float4*)(wts + e0 + q * 4);
        cc[q * 4 + 0] = c4.x; cc[q * 4 + 1] = c4.y; cc[q * 4 + 2] = c4.z; cc[q * 4 + 3] = c4.w;
        ww[q * 4 + 0] = w4.x; ww[q * 4 + 1] = w4.y; ww[q * 4 + 2] = w4.z; ww[q * 4 + 3] = w4.w;
    }

    // issue all 16 gathers before consuming
    unsigned int p[DEG];
    #pragma unroll
    for (int e = 0; e < DEG; ++e)
        p[e] = Ybf2[(size_t)cc[e] * 64 + lane];

    float ax = 0.f, ay = 0.f, den = 0.f;
    #pragma unroll
    for (int e = 0; e < DEG; ++e) {
        const float fx = __uint_as_float(p[e] << 16);
        const float fy = __uint_as_float(p[e] & 0xffff0000u);
        ax = fmaf(ww[e], fx, ax);
        ay = fmaf(ww[e], fy, ay);
        den += ww[e];
    }
    const float inv = 1.0f / den;                       // den >= 0.1*16
    const float2 bv = ((const float2*)bias)[lane];
    float2 o;
    o.x = fmaxf(fmaf(ax, inv, bv.x), 0.f);
    o.y = fmaxf(fmaf(ay, inv, bv.y), 0.f);
    ((float2*)(out + (size_t)node * U_DIM))[lane] = o;
}

extern "C" void kernel_launch(void* const* d_in, const int* in_sizes, int n_in,
                              void* d_out, int out_size, void* d_ws, size_t ws_size,
                              hipStream_t stream) {
    const float* feat = (const float*)d_in[0];
    // d_in[1] = edge_rows: unused — rows are arange(E)//DEG, node i owns edges [16i,16i+16)
    const int* cols  = (const int*)d_in[2];
    const float* wts = (const float*)d_in[3];
    const float* W   = (const float*)d_in[4];
    const float* b   = (const float*)d_in[5];
    float* out = (float*)d_out;

    unsigned short* wt_bf = (unsigned short*)d_ws;                    // 32 KB
    unsigned short* Y     = (unsigned short*)((char*)d_ws + 32768);   // 25.6 MB

    cast_w_kernel<<<16384 / 256, 256, 0, stream>>>(W, wt_bf);

    const int nblocks = (N_NODES + M_TILE - 1) / M_TILE;   // 782
    ymat_kernel<<<nblocks, 256, 0, stream>>>(feat, wt_bf, Y);

    agg_kernel<<<N_NODES / 4, 256, 0, stream>>>(
        (const unsigned int*)Y, cols, wts, b, out);
}